// Round 1
// 338.018 us; speedup vs baseline: 1.1377x; 1.1377x over previous
//
#include <hip/hip_runtime.h>
#include <hip/hip_bf16.h>

#define N_NEURON 1024
#define N_PEPTIDE 16
#define N_GENES 1
#define BATCH 2048
#define SQ 32
#define DT_STEP (1.0f/120.0f)
#define S_STRIDE (N_NEURON + N_GENES + N_NEURON + N_NEURON*N_PEPTIDE) // 18433

typedef __attribute__((ext_vector_type(8))) short short8;
typedef __attribute__((ext_vector_type(4))) short short4v;
typedef __attribute__((ext_vector_type(4))) float floatx4;
// 4-byte-aligned float4: S_STRIDE is odd, so row-relative offsets are only
// dword-aligned. gfx9+ supports unaligned (4B) dwordx4 global access; worst
// case the compiler splits into dword ops (== old scalar behavior).
typedef floatx4 floatx4u __attribute__((aligned(4)));

// -------------------------------------------------------------------------
// Kernel 1: synapse (K x N fp32, row-major) -> synT (N x K bf16, row-major)
// -------------------------------------------------------------------------
__global__ __launch_bounds__(256) void synT_cast(const float* __restrict__ syn,
                                                 __hip_bfloat16* __restrict__ synT) {
    __shared__ float tile[32][33];
    const int n0 = blockIdx.x * 32;
    const int k0 = blockIdx.y * 32;
    const int tx = threadIdx.x & 31;
    const int ty = threadIdx.x >> 5; // 0..7
    #pragma unroll
    for (int i = 0; i < 4; ++i)
        tile[ty + i*8][tx] = syn[(long)(k0 + ty + i*8) * N_NEURON + n0 + tx];
    __syncthreads();
    #pragma unroll
    for (int i = 0; i < 4; ++i)
        synT[(long)(n0 + ty + i*8) * N_NEURON + k0 + tx] =
            __float2bfloat16(tile[tx][ty + i*8]);
}

// -------------------------------------------------------------------------
// Kernel 2: one block per batch row, fully float4-vectorized.
//   Phase 1: firing + masked neuron (float4 loads/stores).
//   Phase 2: peptide update, 4 peptides/thread (float4), pact-dot into LDS.
//   Phase 3: staged c0 written as coalesced float4 pass.
// -------------------------------------------------------------------------
__global__ __launch_bounds__(256) void fused_elem(
    const float* __restrict__ u,
    const float* __restrict__ state,
    const float* __restrict__ noise,
    const float* __restrict__ D,
    const float* __restrict__ prod_g,
    const float* __restrict__ decay_g,
    const float* __restrict__ pact_g,
    const float* __restrict__ ndecay_g,
    const float* __restrict__ inL,
    float* __restrict__ firing_out,
    float* __restrict__ state_new,
    __hip_bfloat16* __restrict__ fbf)
{
    __shared__ float sf[N_NEURON];   // firing
    __shared__ float sn[N_NEURON];   // masked neuron
    __shared__ float sps[N_NEURON];  // peptide . pep_action per neuron
    const int b = blockIdx.x;
    const int tid = threadIdx.x;
    const long bS = (long)b * S_STRIDE;
    const float u_b = u[b];
    const float pc2 = state[bS + N_NEURON];
    const float ndecay = fabsf(ndecay_g[0]);

    // ---- phase 1: firing (256 threads x float4 == 1024 neurons) ----
    {
        const int n4 = tid * 4;
        floatx4 ab = *(const floatx4u*)(state + bS + n4);
        floatx4 nr = *(const floatx4u*)(state + bS + N_NEURON + N_GENES + n4);
        floatx4 nz = *(const floatx4*)(noise + (long)b * N_NEURON + n4);
        floatx4 f, nm;
        short4v hb;
        #pragma unroll
        for (int j = 0; j < 4; ++j) {
            nm[j] = nr[j] * ab[j];
            float fr = fmaxf(nr[j], 0.f) * ab[j];
            fr = -(fr + 0.01f) * log1pf(-nz[j]);
            fr = fminf(fmaxf(fr, 0.f), 10.f);
            f[j] = fr;
            __hip_bfloat16 h = __float2bfloat16(fr);
            hb[j] = *reinterpret_cast<short*>(&h);
        }
        *(floatx4*)(firing_out + (long)b * N_NEURON + n4) = f;
        *(short4v*)(fbf + (long)b * N_NEURON + n4) = hb;
        *(floatx4u*)(state_new + bS + n4) = ab;
        *(floatx4*)(sf + n4) = f;
        *(floatx4*)(sn + n4) = nm;
    }
    if (tid == 0) state_new[bS + N_NEURON] = pc2;
    __syncthreads();

    // ---- phase 2: peptide, float4 over p ----
    const int pq = tid & 3;          // which p-quad (p = pq*4..pq*4+3)
    const int nl = tid >> 2;         // 0..63 neuron sub-index
    const int p0 = pq * 4;
    floatx4 Dq, prq, deq, paq;
    #pragma unroll
    for (int j = 0; j < 4; ++j) {
        Dq[j]  = fabsf(D[p0 + j]);
        prq[j] = fabsf(prod_g[p0 + j]);
        deq[j] = fabsf(decay_g[p0 + j]);
        paq[j] = pact_g[p0 + j];
    }
    const float* __restrict__ pep = state + bS + 2 * N_NEURON + N_GENES;
    float* __restrict__ pep_new = state_new + bS + 2 * N_NEURON + N_GENES;

    #pragma unroll 2
    for (int it = 0; it < 16; ++it) {
        const int n = it * 64 + nl;
        const int si = n >> 5, sj = n & 31;
        const int iup = ((((si + 31) & 31) * 32 + sj) << 4) + p0;
        const int idn = ((((si + 1) & 31) * 32 + sj) << 4) + p0;
        const int ilf = ((si * 32 + ((sj + 31) & 31)) << 4) + p0;
        const int irt = ((si * 32 + ((sj + 1) & 31)) << 4) + p0;
        const int idx = (n << 4) + p0;
        floatx4 c  = *(const floatx4u*)(pep + idx);
        floatx4 vu = *(const floatx4u*)(pep + iup);
        floatx4 vd = *(const floatx4u*)(pep + idn);
        floatx4 vl = *(const floatx4u*)(pep + ilf);
        floatx4 vr = *(const floatx4u*)(pep + irt);
        const float fn = sf[n];
        floatx4 lap = vu + vd + vl + vr - 4.f * c;
        floatx4 outv = c + DT_STEP * (prq * fn - deq * c + Dq * lap);
        *(floatx4u*)(pep_new + idx) = outv;

        float ps = c[0]*paq[0] + c[1]*paq[1] + c[2]*paq[2] + c[3]*paq[3];
        ps += __shfl_xor(ps, 1);
        ps += __shfl_xor(ps, 2);
        if (pq == 0) sps[n] = ps;
    }
    __syncthreads();

    // ---- phase 3: staged c0, coalesced float4 ----
    {
        const int n4 = tid * 4;
        floatx4 ss = *(const floatx4*)(sps + n4);
        floatx4 nm = *(const floatx4*)(sn + n4);
        floatx4 il = *(const floatx4*)(inL + n4);
        floatx4 c0;
        #pragma unroll
        for (int j = 0; j < 4; ++j)
            c0[j] = nm[j] + DT_STEP * (ss[j] * pc2 - nm[j] * ndecay + il[j] * u_b);
        *(floatx4u*)(state_new + bS + N_NEURON + N_GENES + n4) = c0;
    }
}

// -------------------------------------------------------------------------
// Kernel 3: bf16 MFMA GEMM, 64x64 block tile, BK=64, double-buffered LDS
// via global_load_lds(16B) with source-side XOR swizzle (T2/m173 pattern:
// linear LDS dest, inverse-swizzled global source, swizzled ds_read).
// 4 waves of 32x32; fused epilogue neuron_new = (c0 + DT*gemm)*ablate.
// -------------------------------------------------------------------------
__device__ __forceinline__ void stage8k(const __hip_bfloat16* __restrict__ gbase,
                                        char* lhalf, int row0, int k0,
                                        int w, int lane)
{
    // stages 64 rows x 64 cols bf16 (8KB); wave w handles chunks w*2, w*2+1
    #pragma unroll
    for (int i = 0; i < 2; ++i) {
        const int ch  = w * 2 + i;                // 0..7, 1KB each
        const int o   = ch * 1024 + lane * 16;    // linear byte offset in half
        const int row = o >> 7;                   // 0..63
        const int c16 = (o >> 4) & 7;             // 16B chunk within row
        const int cl  = c16 ^ (row & 7);          // inverse swizzle on source
        const __hip_bfloat16* g = gbase + (long)(row0 + row) * 1024 + k0 + cl * 8;
        __builtin_amdgcn_global_load_lds(
            (const __attribute__((address_space(1))) void*)g,
            (__attribute__((address_space(3))) void*)(lhalf + ch * 1024),
            16, 0, 0);
    }
}

__device__ __forceinline__ short8 lds_frag(const char* lhalf, int row, int c16) {
    const int cl = c16 ^ (row & 7);               // swizzled read
    return *(const short8*)(lhalf + row * 128 + cl * 16);
}

__global__ __launch_bounds__(256) void gemm_epi(
    const __hip_bfloat16* __restrict__ A,   // firing bf16 [2048,1024]
    const __hip_bfloat16* __restrict__ BT,  // synT bf16 [1024,1024]
    const float* __restrict__ state,
    float* __restrict__ state_new)
{
    __shared__ __align__(16) char lds[2][16384]; // [buf][A 8KB | B 8KB]
    const int tid = threadIdx.x;
    const int w = tid >> 6, lane = tid & 63;
    const int q = lane >> 4, l16 = lane & 15;
    const int m0 = blockIdx.x * 64;
    const int n0 = blockIdx.y * 64;
    const int wm = (w & 1) * 32, wn = (w >> 1) * 32;

    floatx4 acc[2][2] = {};

    stage8k(A,  lds[0],        m0, 0, w, lane);
    stage8k(BT, lds[0] + 8192, n0, 0, w, lane);
    __syncthreads();                          // buf0 ready (implies vmcnt(0))

    int cur = 0;
    for (int t = 0; t < 16; ++t) {
        if (t < 15) {                          // issue next-tile loads first
            stage8k(A,  lds[cur ^ 1],        m0, (t + 1) * 64, w, lane);
            stage8k(BT, lds[cur ^ 1] + 8192, n0, (t + 1) * 64, w, lane);
        }
        const char* la = lds[cur];
        const char* lb = lds[cur] + 8192;
        #pragma unroll
        for (int kk = 0; kk < 2; ++kk) {
            const int c16 = kk * 4 + q;
            short8 a0 = lds_frag(la, wm + l16,      c16);
            short8 a1 = lds_frag(la, wm + 16 + l16, c16);
            short8 b0 = lds_frag(lb, wn + l16,      c16);
            short8 b1 = lds_frag(lb, wn + 16 + l16, c16);
            acc[0][0] = __builtin_amdgcn_mfma_f32_16x16x32_bf16(a0, b0, acc[0][0], 0, 0, 0);
            acc[0][1] = __builtin_amdgcn_mfma_f32_16x16x32_bf16(a0, b1, acc[0][1], 0, 0, 0);
            acc[1][0] = __builtin_amdgcn_mfma_f32_16x16x32_bf16(a1, b0, acc[1][0], 0, 0, 0);
            acc[1][1] = __builtin_amdgcn_mfma_f32_16x16x32_bf16(a1, b1, acc[1][1], 0, 0, 0);
        }
        if (t < 15) __syncthreads();          // drain prefetch + guard reuse
        cur ^= 1;
    }

    #pragma unroll
    for (int mi = 0; mi < 2; ++mi)
    #pragma unroll
    for (int ni = 0; ni < 2; ++ni)
    #pragma unroll
    for (int r = 0; r < 4; ++r) {
        const int m = m0 + wm + mi * 16 + q * 4 + r;
        const int n = n0 + wn + ni * 16 + l16;
        const long sidx = (long)m * S_STRIDE;
        const float ab = state[sidx + n];
        const float c0 = state_new[sidx + N_NEURON + N_GENES + n];
        state_new[sidx + N_NEURON + N_GENES + n] = (c0 + DT_STEP * acc[mi][ni][r]) * ab;
    }
}

extern "C" void kernel_launch(void* const* d_in, const int* in_sizes, int n_in,
                              void* d_out, int out_size, void* d_ws, size_t ws_size,
                              hipStream_t stream) {
    const float* u      = (const float*)d_in[0];
    const float* state  = (const float*)d_in[1];
    const float* noise  = (const float*)d_in[2];
    const float* D      = (const float*)d_in[3];
    const float* prod   = (const float*)d_in[4];
    const float* decay  = (const float*)d_in[5];
    const float* pact   = (const float*)d_in[6];
    const float* syn    = (const float*)d_in[7];
    const float* ndec   = (const float*)d_in[8];
    const float* inL    = (const float*)d_in[9];

    float* firing = (float*)d_out;                          // [B,N]
    float* state_new = firing + (long)BATCH * N_NEURON;     // [B,S]

    __hip_bfloat16* fbf  = (__hip_bfloat16*)d_ws;           // 4 MB
    __hip_bfloat16* synT = fbf + (long)BATCH * N_NEURON;    // 2 MB

    hipLaunchKernelGGL(synT_cast, dim3(32, 32), dim3(256), 0, stream, syn, synT);
    hipLaunchKernelGGL(fused_elem, dim3(BATCH), dim3(256), 0, stream,
                       u, state, noise, D, prod, decay, pact, ndec, inL,
                       firing, state_new, fbf);
    hipLaunchKernelGGL(gemm_epi, dim3(32, 16), dim3(256), 0, stream,
                       fbf, synT, state, state_new);
}

// Round 2
// 319.231 us; speedup vs baseline: 1.2046x; 1.0588x over previous
//
#include <hip/hip_runtime.h>
#include <hip/hip_bf16.h>

#define N_NEURON 1024
#define N_PEPTIDE 16
#define N_GENES 1
#define BATCH 2048
#define SQ 32
#define DT_STEP (1.0f/120.0f)
#define S_STRIDE (N_NEURON + N_GENES + N_NEURON + N_NEURON*N_PEPTIDE) // 18433

typedef __attribute__((ext_vector_type(8))) short short8;
typedef __attribute__((ext_vector_type(4))) short short4v;
typedef __attribute__((ext_vector_type(4))) float floatx4;
// 4-byte-aligned float4: S_STRIDE is odd, so row-relative offsets are only
// dword-aligned. gfx9+ handles 4B-aligned dwordx4 global access.
typedef floatx4 floatx4u __attribute__((aligned(4)));

// -------------------------------------------------------------------------
// Kernel 1: synapse (K x N fp32, row-major) -> synT (N x K bf16, row-major)
// -------------------------------------------------------------------------
__global__ __launch_bounds__(256) void synT_cast(const float* __restrict__ syn,
                                                 __hip_bfloat16* __restrict__ synT) {
    __shared__ float tile[32][33];
    const int n0 = blockIdx.x * 32;
    const int k0 = blockIdx.y * 32;
    const int tx = threadIdx.x & 31;
    const int ty = threadIdx.x >> 5; // 0..7
    #pragma unroll
    for (int i = 0; i < 4; ++i)
        tile[ty + i*8][tx] = syn[(long)(k0 + ty + i*8) * N_NEURON + n0 + tx];
    __syncthreads();
    #pragma unroll
    for (int i = 0; i < 4; ++i)
        synT[(long)(n0 + ty + i*8) * N_NEURON + k0 + tx] =
            __float2bfloat16(tile[tx][ty + i*8]);
}

// -------------------------------------------------------------------------
// Kernel 2: one block per batch row.
//   Phase 2 restructured: 4 batches x 4 iters, each batch issues all 20
//   float4 stencil loads into registers before computing (explicit MLP).
//   Batch 0's loads are hoisted ABOVE phase 1 so they fly during firing.
// -------------------------------------------------------------------------
__global__ __launch_bounds__(256) void fused_elem(
    const float* __restrict__ u,
    const float* __restrict__ state,
    const float* __restrict__ noise,
    const float* __restrict__ D,
    const float* __restrict__ prod_g,
    const float* __restrict__ decay_g,
    const float* __restrict__ pact_g,
    const float* __restrict__ ndecay_g,
    const float* __restrict__ inL,
    float* __restrict__ firing_out,
    float* __restrict__ state_new,
    __hip_bfloat16* __restrict__ fbf)
{
    __shared__ float sf[N_NEURON];   // firing
    __shared__ float sn[N_NEURON];   // masked neuron
    __shared__ float sps[N_NEURON];  // peptide . pep_action per neuron
    const int b = blockIdx.x;
    const int tid = threadIdx.x;
    const long bS = (long)b * S_STRIDE;
    const float u_b = u[b];
    const float pc2 = state[bS + N_NEURON];
    const float ndecay = fabsf(ndecay_g[0]);

    // phase-2 constants (per-thread p-quad)
    const int pq = tid & 3;          // which p-quad (p = pq*4..pq*4+3)
    const int nl = tid >> 2;         // 0..63 neuron sub-index
    const int p0 = pq * 4;
    floatx4 Dq, prq, deq, paq;
    #pragma unroll
    for (int j = 0; j < 4; ++j) {
        Dq[j]  = fabsf(D[p0 + j]);
        prq[j] = fabsf(prod_g[p0 + j]);
        deq[j] = fabsf(decay_g[p0 + j]);
        paq[j] = pact_g[p0 + j];
    }
    const float* __restrict__ pep = state + bS + 2 * N_NEURON + N_GENES;
    float* __restrict__ pep_new = state_new + bS + 2 * N_NEURON + N_GENES;

    // phase-2 register batch (4 iterations x 5 float4 = 20 loads in flight)
    floatx4 c[4], vu[4], vd[4], vl[4], vr[4];
    int idxs[4];

#define LOADB(ob)                                                             \
    _Pragma("unroll")                                                         \
    for (int s = 0; s < 4; ++s) {                                             \
        const int n = ((ob) * 4 + s) * 64 + nl;                               \
        const int si = n >> 5, sj = n & 31;                                   \
        idxs[s] = (n << 4) + p0;                                              \
        c[s]  = *(const floatx4u*)(pep + idxs[s]);                            \
        vu[s] = *(const floatx4u*)(pep + ((((si + 31) & 31) * 32 + sj) << 4) + p0); \
        vd[s] = *(const floatx4u*)(pep + ((((si +  1) & 31) * 32 + sj) << 4) + p0); \
        vl[s] = *(const floatx4u*)(pep + ((si * 32 + ((sj + 31) & 31)) << 4) + p0); \
        vr[s] = *(const floatx4u*)(pep + ((si * 32 + ((sj +  1) & 31)) << 4) + p0); \
    }

#define COMPB(ob)                                                             \
    _Pragma("unroll")                                                         \
    for (int s = 0; s < 4; ++s) {                                             \
        const int n = ((ob) * 4 + s) * 64 + nl;                               \
        const float fn = sf[n];                                               \
        floatx4 lap = vu[s] + vd[s] + vl[s] + vr[s] - 4.f * c[s];             \
        floatx4 outv = c[s] + DT_STEP * (prq * fn - deq * c[s] + Dq * lap);   \
        *(floatx4u*)(pep_new + idxs[s]) = outv;                               \
        float ps = c[s][0]*paq[0] + c[s][1]*paq[1] + c[s][2]*paq[2] + c[s][3]*paq[3]; \
        ps += __shfl_xor(ps, 1);                                              \
        ps += __shfl_xor(ps, 2);                                              \
        if (pq == 0) sps[n] = ps;                                             \
    }

    // issue batch-0 stencil loads: they complete during phase 1
    LOADB(0)

    // ---- phase 1: firing (256 threads x float4 == 1024 neurons) ----
    {
        const int n4 = tid * 4;
        floatx4 ab = *(const floatx4u*)(state + bS + n4);
        floatx4 nr = *(const floatx4u*)(state + bS + N_NEURON + N_GENES + n4);
        floatx4 nz = *(const floatx4*)(noise + (long)b * N_NEURON + n4);
        floatx4 f, nm;
        short4v hb;
        #pragma unroll
        for (int j = 0; j < 4; ++j) {
            nm[j] = nr[j] * ab[j];
            float fr = fmaxf(nr[j], 0.f) * ab[j];
            fr = -(fr + 0.01f) * log1pf(-nz[j]);
            fr = fminf(fmaxf(fr, 0.f), 10.f);
            f[j] = fr;
            __hip_bfloat16 h = __float2bfloat16(fr);
            hb[j] = *reinterpret_cast<short*>(&h);
        }
        *(floatx4*)(firing_out + (long)b * N_NEURON + n4) = f;
        *(short4v*)(fbf + (long)b * N_NEURON + n4) = hb;
        *(floatx4u*)(state_new + bS + n4) = ab;
        *(floatx4*)(sf + n4) = f;
        *(floatx4*)(sn + n4) = nm;
    }
    if (tid == 0) state_new[bS + N_NEURON] = pc2;
    __syncthreads();

    // ---- phase 2: peptide, batched ----
    COMPB(0)
    #pragma unroll
    for (int ob = 1; ob < 4; ++ob) {
        LOADB(ob)
        COMPB(ob)
    }
#undef LOADB
#undef COMPB
    __syncthreads();

    // ---- phase 3: staged c0, coalesced float4 ----
    {
        const int n4 = tid * 4;
        floatx4 ss = *(const floatx4*)(sps + n4);
        floatx4 nm = *(const floatx4*)(sn + n4);
        floatx4 il = *(const floatx4*)(inL + n4);
        floatx4 c0;
        #pragma unroll
        for (int j = 0; j < 4; ++j)
            c0[j] = nm[j] + DT_STEP * (ss[j] * pc2 - nm[j] * ndecay + il[j] * u_b);
        *(floatx4u*)(state_new + bS + N_NEURON + N_GENES + n4) = c0;
    }
}

// -------------------------------------------------------------------------
// Kernel 3: bf16 MFMA GEMM (unchanged this round — clean A/B on fused_elem).
// -------------------------------------------------------------------------
__device__ __forceinline__ void stage8k(const __hip_bfloat16* __restrict__ gbase,
                                        char* lhalf, int row0, int k0,
                                        int w, int lane)
{
    #pragma unroll
    for (int i = 0; i < 2; ++i) {
        const int ch  = w * 2 + i;                // 0..7, 1KB each
        const int o   = ch * 1024 + lane * 16;    // linear byte offset in half
        const int row = o >> 7;                   // 0..63
        const int c16 = (o >> 4) & 7;             // 16B chunk within row
        const int cl  = c16 ^ (row & 7);          // inverse swizzle on source
        const __hip_bfloat16* g = gbase + (long)(row0 + row) * 1024 + k0 + cl * 8;
        __builtin_amdgcn_global_load_lds(
            (const __attribute__((address_space(1))) void*)g,
            (__attribute__((address_space(3))) void*)(lhalf + ch * 1024),
            16, 0, 0);
    }
}

__device__ __forceinline__ short8 lds_frag(const char* lhalf, int row, int c16) {
    const int cl = c16 ^ (row & 7);               // swizzled read
    return *(const short8*)(lhalf + row * 128 + cl * 16);
}

__global__ __launch_bounds__(256) void gemm_epi(
    const __hip_bfloat16* __restrict__ A,   // firing bf16 [2048,1024]
    const __hip_bfloat16* __restrict__ BT,  // synT bf16 [1024,1024]
    const float* __restrict__ state,
    float* __restrict__ state_new)
{
    __shared__ __align__(16) char lds[2][16384]; // [buf][A 8KB | B 8KB]
    const int tid = threadIdx.x;
    const int w = tid >> 6, lane = tid & 63;
    const int q = lane >> 4, l16 = lane & 15;
    const int m0 = blockIdx.x * 64;
    const int n0 = blockIdx.y * 64;
    const int wm = (w & 1) * 32, wn = (w >> 1) * 32;

    floatx4 acc[2][2] = {};

    stage8k(A,  lds[0],        m0, 0, w, lane);
    stage8k(BT, lds[0] + 8192, n0, 0, w, lane);
    __syncthreads();

    int cur = 0;
    for (int t = 0; t < 16; ++t) {
        if (t < 15) {                          // issue next-tile loads first
            stage8k(A,  lds[cur ^ 1],        m0, (t + 1) * 64, w, lane);
            stage8k(BT, lds[cur ^ 1] + 8192, n0, (t + 1) * 64, w, lane);
        }
        const char* la = lds[cur];
        const char* lb = lds[cur] + 8192;
        #pragma unroll
        for (int kk = 0; kk < 2; ++kk) {
            const int c16 = kk * 4 + q;
            short8 a0 = lds_frag(la, wm + l16,      c16);
            short8 a1 = lds_frag(la, wm + 16 + l16, c16);
            short8 b0 = lds_frag(lb, wn + l16,      c16);
            short8 b1 = lds_frag(lb, wn + 16 + l16, c16);
            acc[0][0] = __builtin_amdgcn_mfma_f32_16x16x32_bf16(a0, b0, acc[0][0], 0, 0, 0);
            acc[0][1] = __builtin_amdgcn_mfma_f32_16x16x32_bf16(a0, b1, acc[0][1], 0, 0, 0);
            acc[1][0] = __builtin_amdgcn_mfma_f32_16x16x32_bf16(a1, b0, acc[1][0], 0, 0, 0);
            acc[1][1] = __builtin_amdgcn_mfma_f32_16x16x32_bf16(a1, b1, acc[1][1], 0, 0, 0);
        }
        if (t < 15) __syncthreads();
        cur ^= 1;
    }

    #pragma unroll
    for (int mi = 0; mi < 2; ++mi)
    #pragma unroll
    for (int ni = 0; ni < 2; ++ni)
    #pragma unroll
    for (int r = 0; r < 4; ++r) {
        const int m = m0 + wm + mi * 16 + q * 4 + r;
        const int n = n0 + wn + ni * 16 + l16;
        const long sidx = (long)m * S_STRIDE;
        const float ab = state[sidx + n];
        const float c0 = state_new[sidx + N_NEURON + N_GENES + n];
        state_new[sidx + N_NEURON + N_GENES + n] = (c0 + DT_STEP * acc[mi][ni][r]) * ab;
    }
}

extern "C" void kernel_launch(void* const* d_in, const int* in_sizes, int n_in,
                              void* d_out, int out_size, void* d_ws, size_t ws_size,
                              hipStream_t stream) {
    const float* u      = (const float*)d_in[0];
    const float* state  = (const float*)d_in[1];
    const float* noise  = (const float*)d_in[2];
    const float* D      = (const float*)d_in[3];
    const float* prod   = (const float*)d_in[4];
    const float* decay  = (const float*)d_in[5];
    const float* pact   = (const float*)d_in[6];
    const float* syn    = (const float*)d_in[7];
    const float* ndec   = (const float*)d_in[8];
    const float* inL    = (const float*)d_in[9];

    float* firing = (float*)d_out;                          // [B,N]
    float* state_new = firing + (long)BATCH * N_NEURON;     // [B,S]

    __hip_bfloat16* fbf  = (__hip_bfloat16*)d_ws;           // 4 MB
    __hip_bfloat16* synT = fbf + (long)BATCH * N_NEURON;    // 2 MB

    hipLaunchKernelGGL(synT_cast, dim3(32, 32), dim3(256), 0, stream, syn, synT);
    hipLaunchKernelGGL(fused_elem, dim3(BATCH), dim3(256), 0, stream,
                       u, state, noise, D, prod, decay, pact, ndec, inL,
                       firing, state_new, fbf);
    hipLaunchKernelGGL(gemm_epi, dim3(32, 16), dim3(256), 0, stream,
                       fbf, synT, state, state_new);
}

// Round 3
// 316.229 us; speedup vs baseline: 1.2160x; 1.0095x over previous
//
#include <hip/hip_runtime.h>
#include <hip/hip_bf16.h>

#define N_NEURON 1024
#define N_PEPTIDE 16
#define N_GENES 1
#define BATCH 2048
#define SQ 32
#define DT_STEP (1.0f/120.0f)
#define S_STRIDE (N_NEURON + N_GENES + N_NEURON + N_NEURON*N_PEPTIDE) // 18433

typedef __attribute__((ext_vector_type(8))) short short8;
typedef __attribute__((ext_vector_type(4))) float floatx4;
typedef __attribute__((ext_vector_type(2))) float floatx2;
// S_STRIDE is odd, so state-relative offsets are only dword-aligned.
typedef floatx4 floatx4u __attribute__((aligned(4)));
typedef floatx2 floatx2u __attribute__((aligned(4)));

// -------------------------------------------------------------------------
// Kernel 1: synapse (K x N fp32, row-major) -> synT (N x K bf16, row-major)
// -------------------------------------------------------------------------
__global__ __launch_bounds__(256) void synT_cast(const float* __restrict__ syn,
                                                 __hip_bfloat16* __restrict__ synT) {
    __shared__ float tile[32][33];
    const int n0 = blockIdx.x * 32;
    const int k0 = blockIdx.y * 32;
    const int tx = threadIdx.x & 31;
    const int ty = threadIdx.x >> 5; // 0..7
    #pragma unroll
    for (int i = 0; i < 4; ++i)
        tile[ty + i*8][tx] = syn[(long)(k0 + ty + i*8) * N_NEURON + n0 + tx];
    __syncthreads();
    #pragma unroll
    for (int i = 0; i < 4; ++i)
        synT[(long)(n0 + ty + i*8) * N_NEURON + k0 + tx] =
            __float2bfloat16(tile[tx][ty + i*8]);
}

// -------------------------------------------------------------------------
// Kernel 2: block = (batch row, half grid). LDS-stage 16+2 halo stencil rows
// (36 KB) so each peptide value is read from global exactly ~1.13x instead
// of 5x (the 5-pt stencil re-reads were L3-BW-bound at ~7 TB/s logical).
// Firing + ablate copy + staged c0 for the block's 512 neurons done in-block.
// -------------------------------------------------------------------------
__global__ __launch_bounds__(256) void pep_fused(
    const float* __restrict__ u,
    const float* __restrict__ state,
    const float* __restrict__ noise,
    const float* __restrict__ D,
    const float* __restrict__ prod_g,
    const float* __restrict__ decay_g,
    const float* __restrict__ pact_g,
    const float* __restrict__ ndecay_g,
    const float* __restrict__ inL,
    float* __restrict__ firing_out,
    float* __restrict__ state_new,
    __hip_bfloat16* __restrict__ fbf)
{
    __shared__ floatx4 slab4[18 * 128];   // [row 0..17][32 sj * 4 pq], 36 KB
    __shared__ float sf[512];             // firing (block-local)
    __shared__ float sn[512];             // masked neuron
    __shared__ float sps[512];            // peptide . pep_action

    const int b   = blockIdx.x >> 1;
    const int h   = blockIdx.x & 1;      // which half of the 32x32 grid
    const int tid = threadIdx.x;
    const long bS = (long)b * S_STRIDE;
    const int r0  = h * 16;              // first owned si-row
    const float u_b  = u[b];
    const float pc2  = state[bS + N_NEURON];
    const float ndecay = fabsf(ndecay_g[0]);

    const float* __restrict__ pep = state + bS + 2 * N_NEURON + N_GENES;
    float* __restrict__ pep_new = state_new + bS + 2 * N_NEURON + N_GENES;

    // ---- issue slab loads (16 owned rows + 2 halo rows) into registers ----
    floatx4 sl[8];
    #pragma unroll
    for (int k = 0; k < 8; ++k)
        sl[k] = *(const floatx4u*)(pep + r0 * 512 + (tid + k * 256) * 4);
    floatx4 halo;
    {
        const int hr = (tid < 128) ? ((r0 + 31) & 31) : ((r0 + 16) & 31);
        const int ht = tid & 127;
        halo = *(const floatx4u*)(pep + hr * 512 + ht * 4);
    }

    // ---- phase 1 loads: firing for this block's 512 neurons (2/thread) ----
    const int gn = h * 512 + tid * 2;    // global neuron index (even)
    floatx2 abv = *(const floatx2u*)(state + bS + gn);
    floatx2 nrv = *(const floatx2u*)(state + bS + N_NEURON + N_GENES + gn);
    floatx2 nzv = *(const floatx2*)(noise + (long)b * N_NEURON + gn);

    // ---- stage slab into LDS (waits on slab loads only) ----
    #pragma unroll
    for (int k = 0; k < 8; ++k)
        slab4[128 + tid + k * 256] = sl[k];   // owned rows -> local rows 1..16
    if (tid < 128) slab4[tid] = halo;         // up halo -> row 0
    else           slab4[2176 + tid - 128] = halo; // down halo -> row 17

    // ---- phase 1 compute ----
    {
        floatx2 fv, nmv;
        #pragma unroll
        for (int j = 0; j < 2; ++j) {
            nmv[j] = nrv[j] * abv[j];
            float fr = fmaxf(nrv[j], 0.f) * abv[j];
            fr = -(fr + 0.01f) * log1pf(-nzv[j]);
            fr = fminf(fmaxf(fr, 0.f), 10.f);
            fv[j] = fr;
        }
        *(floatx2*)(firing_out + (long)b * N_NEURON + gn) = fv;
        __hip_bfloat16 h0 = __float2bfloat16(fv[0]);
        __hip_bfloat16 h1 = __float2bfloat16(fv[1]);
        unsigned int packed = (unsigned int)(*(unsigned short*)&h0) |
                              ((unsigned int)(*(unsigned short*)&h1) << 16);
        *(unsigned int*)(fbf + (long)b * N_NEURON + gn) = packed;
        *(floatx2u*)(state_new + bS + gn) = abv;   // ablate copy
        *(floatx2*)(sf + tid * 2) = fv;
        *(floatx2*)(sn + tid * 2) = nmv;
    }
    if (h == 0 && tid == 0) state_new[bS + N_NEURON] = pc2;
    __syncthreads();

    // ---- phase 2: stencil from LDS ----
    const int pq = tid & 3;              // p-quad 0..3
    const int nl = tid >> 2;             // 0..63
    const int p0q = pq * 4;
    floatx4 Dq, prq, deq, paq;
    #pragma unroll
    for (int j = 0; j < 4; ++j) {
        Dq[j]  = fabsf(D[p0q + j]);
        prq[j] = fabsf(prod_g[p0q + j]);
        deq[j] = fabsf(decay_g[p0q + j]);
        paq[j] = pact_g[p0q + j];
    }

    #pragma unroll 2
    for (int it = 0; it < 8; ++it) {
        const int n_l  = it * 64 + nl;         // 0..511 block-local neuron
        const int si_l = (n_l >> 5) + 1;       // 1..16 (local row)
        const int sj   = n_l & 31;
        const floatx4 c  = slab4[(si_l * 32 + sj) * 4 + pq];
        const floatx4 vu = slab4[((si_l - 1) * 32 + sj) * 4 + pq];
        const floatx4 vd = slab4[((si_l + 1) * 32 + sj) * 4 + pq];
        const floatx4 vl = slab4[(si_l * 32 + ((sj + 31) & 31)) * 4 + pq];
        const floatx4 vr = slab4[(si_l * 32 + ((sj + 1) & 31)) * 4 + pq];
        const float fn = sf[n_l];
        floatx4 lap = vu + vd + vl + vr - 4.f * c;
        floatx4 outv = c + DT_STEP * (prq * fn - deq * c + Dq * lap);
        *(floatx4u*)(pep_new + ((h * 512 + n_l) << 4) + p0q) = outv;

        float ps = c[0]*paq[0] + c[1]*paq[1] + c[2]*paq[2] + c[3]*paq[3];
        ps += __shfl_xor(ps, 1);
        ps += __shfl_xor(ps, 2);
        if (pq == 0) sps[n_l] = ps;
    }
    __syncthreads();

    // ---- phase 3: staged c0 (2 neurons/thread, coalesced) ----
    {
        const int n2  = tid * 2;
        const int gn2 = h * 512 + n2;
        floatx2 ss = *(const floatx2*)(sps + n2);
        floatx2 nm = *(const floatx2*)(sn + n2);
        floatx2 il = *(const floatx2*)(inL + gn2);
        floatx2 c0;
        #pragma unroll
        for (int j = 0; j < 2; ++j)
            c0[j] = nm[j] + DT_STEP * (ss[j] * pc2 - nm[j] * ndecay + il[j] * u_b);
        *(floatx2u*)(state_new + bS + N_NEURON + N_GENES + gn2) = c0;
    }
}

// -------------------------------------------------------------------------
// Kernel 3: bf16 MFMA GEMM, 64x64 tile, BK=64, double-buffered LDS.
// This round: epilogue ab/c0 prefetched before the K-loop (hides their
// L3 latency under MFMA), t-loop unrolled x2 so 'cur' is compile-time.
// -------------------------------------------------------------------------
__device__ __forceinline__ void stage8k(const __hip_bfloat16* __restrict__ gbase,
                                        char* lhalf, int row0, int k0,
                                        int w, int lane)
{
    #pragma unroll
    for (int i = 0; i < 2; ++i) {
        const int ch  = w * 2 + i;                // 0..7, 1KB each
        const int o   = ch * 1024 + lane * 16;    // linear byte offset in half
        const int row = o >> 7;                   // 0..63
        const int c16 = (o >> 4) & 7;             // 16B chunk within row
        const int cl  = c16 ^ (row & 7);          // inverse swizzle on source
        const __hip_bfloat16* g = gbase + (long)(row0 + row) * 1024 + k0 + cl * 8;
        __builtin_amdgcn_global_load_lds(
            (const __attribute__((address_space(1))) void*)g,
            (__attribute__((address_space(3))) void*)(lhalf + ch * 1024),
            16, 0, 0);
    }
}

__device__ __forceinline__ short8 lds_frag(const char* lhalf, int row, int c16) {
    const int cl = c16 ^ (row & 7);               // swizzled read
    return *(const short8*)(lhalf + row * 128 + cl * 16);
}

__global__ __launch_bounds__(256) void gemm_epi(
    const __hip_bfloat16* __restrict__ A,   // firing bf16 [2048,1024]
    const __hip_bfloat16* __restrict__ BT,  // synT bf16 [1024,1024]
    const float* __restrict__ state,
    float* __restrict__ state_new)
{
    __shared__ __align__(16) char lds[2][16384]; // [buf][A 8KB | B 8KB]
    const int tid = threadIdx.x;
    const int w = tid >> 6, lane = tid & 63;
    const int q = lane >> 4, l16 = lane & 15;
    const int m0 = blockIdx.x * 64;
    const int n0 = blockIdx.y * 64;
    const int wm = (w & 1) * 32, wn = (w >> 1) * 32;

    // prefetch epilogue operands; latency hides under the K-loop
    float abv[2][2][4], c0v[2][2][4];
    #pragma unroll
    for (int mi = 0; mi < 2; ++mi)
    #pragma unroll
    for (int ni = 0; ni < 2; ++ni)
    #pragma unroll
    for (int r = 0; r < 4; ++r) {
        const int m = m0 + wm + mi * 16 + q * 4 + r;
        const int n = n0 + wn + ni * 16 + l16;
        const long sidx = (long)m * S_STRIDE;
        abv[mi][ni][r] = state[sidx + n];
        c0v[mi][ni][r] = state_new[sidx + N_NEURON + N_GENES + n];
    }

    floatx4 acc[2][2] = {};

    stage8k(A,  lds[0],        m0, 0, w, lane);
    stage8k(BT, lds[0] + 8192, n0, 0, w, lane);
    __syncthreads();

#define GEMM_STEP(CUR, T)                                                     \
    {                                                                         \
        if ((T) < 15) {                                                       \
            stage8k(A,  lds[(CUR) ^ 1],        m0, ((T) + 1) * 64, w, lane);  \
            stage8k(BT, lds[(CUR) ^ 1] + 8192, n0, ((T) + 1) * 64, w, lane);  \
        }                                                                     \
        const char* la = lds[(CUR)];                                          \
        const char* lb = lds[(CUR)] + 8192;                                   \
        _Pragma("unroll")                                                     \
        for (int kk = 0; kk < 2; ++kk) {                                      \
            const int c16 = kk * 4 + q;                                       \
            short8 a0 = lds_frag(la, wm + l16,      c16);                     \
            short8 a1 = lds_frag(la, wm + 16 + l16, c16);                     \
            short8 b0 = lds_frag(lb, wn + l16,      c16);                     \
            short8 b1 = lds_frag(lb, wn + 16 + l16, c16);                     \
            acc[0][0] = __builtin_amdgcn_mfma_f32_16x16x32_bf16(a0, b0, acc[0][0], 0, 0, 0); \
            acc[0][1] = __builtin_amdgcn_mfma_f32_16x16x32_bf16(a0, b1, acc[0][1], 0, 0, 0); \
            acc[1][0] = __builtin_amdgcn_mfma_f32_16x16x32_bf16(a1, b0, acc[1][0], 0, 0, 0); \
            acc[1][1] = __builtin_amdgcn_mfma_f32_16x16x32_bf16(a1, b1, acc[1][1], 0, 0, 0); \
        }                                                                     \
        if ((T) < 15) __syncthreads();                                        \
    }

    #pragma unroll
    for (int tt = 0; tt < 8; ++tt) {
        GEMM_STEP(0, tt * 2)
        GEMM_STEP(1, tt * 2 + 1)
    }
#undef GEMM_STEP

    #pragma unroll
    for (int mi = 0; mi < 2; ++mi)
    #pragma unroll
    for (int ni = 0; ni < 2; ++ni)
    #pragma unroll
    for (int r = 0; r < 4; ++r) {
        const int m = m0 + wm + mi * 16 + q * 4 + r;
        const int n = n0 + wn + ni * 16 + l16;
        const long sidx = (long)m * S_STRIDE;
        state_new[sidx + N_NEURON + N_GENES + n] =
            (c0v[mi][ni][r] + DT_STEP * acc[mi][ni][r]) * abv[mi][ni][r];
    }
}

extern "C" void kernel_launch(void* const* d_in, const int* in_sizes, int n_in,
                              void* d_out, int out_size, void* d_ws, size_t ws_size,
                              hipStream_t stream) {
    const float* u      = (const float*)d_in[0];
    const float* state  = (const float*)d_in[1];
    const float* noise  = (const float*)d_in[2];
    const float* D      = (const float*)d_in[3];
    const float* prod   = (const float*)d_in[4];
    const float* decay  = (const float*)d_in[5];
    const float* pact   = (const float*)d_in[6];
    const float* syn    = (const float*)d_in[7];
    const float* ndec   = (const float*)d_in[8];
    const float* inL    = (const float*)d_in[9];

    float* firing = (float*)d_out;                          // [B,N]
    float* state_new = firing + (long)BATCH * N_NEURON;     // [B,S]

    __hip_bfloat16* fbf  = (__hip_bfloat16*)d_ws;           // 4 MB
    __hip_bfloat16* synT = fbf + (long)BATCH * N_NEURON;    // 2 MB

    hipLaunchKernelGGL(synT_cast, dim3(32, 32), dim3(256), 0, stream, syn, synT);
    hipLaunchKernelGGL(pep_fused, dim3(BATCH * 2), dim3(256), 0, stream,
                       u, state, noise, D, prod, decay, pact, ndec, inL,
                       firing, state_new, fbf);
    hipLaunchKernelGGL(gemm_epi, dim3(32, 16), dim3(256), 0, stream,
                       fbf, synT, state, state_new);
}

// Round 4
// 316.147 us; speedup vs baseline: 1.2164x; 1.0003x over previous
//
#include <hip/hip_runtime.h>
#include <hip/hip_bf16.h>

#define N_NEURON 1024
#define N_PEPTIDE 16
#define N_GENES 1
#define BATCH 2048
#define SQ 32
#define DT_STEP (1.0f/120.0f)
#define S_STRIDE (N_NEURON + N_GENES + N_NEURON + N_NEURON*N_PEPTIDE) // 18433

typedef __attribute__((ext_vector_type(8))) short short8;
typedef __attribute__((ext_vector_type(4))) float floatx4;
typedef __attribute__((ext_vector_type(2))) float floatx2;
// S_STRIDE is odd, so state-relative offsets are only dword-aligned.
typedef floatx4 floatx4u __attribute__((aligned(4)));
typedef floatx2 floatx2u __attribute__((aligned(4)));

// -------------------------------------------------------------------------
// Kernel 1: synapse (K x N fp32, row-major) -> synT (N x K bf16, row-major)
// -------------------------------------------------------------------------
__global__ __launch_bounds__(256) void synT_cast(const float* __restrict__ syn,
                                                 __hip_bfloat16* __restrict__ synT) {
    __shared__ float tile[32][33];
    const int n0 = blockIdx.x * 32;
    const int k0 = blockIdx.y * 32;
    const int tx = threadIdx.x & 31;
    const int ty = threadIdx.x >> 5; // 0..7
    #pragma unroll
    for (int i = 0; i < 4; ++i)
        tile[ty + i*8][tx] = syn[(long)(k0 + ty + i*8) * N_NEURON + n0 + tx];
    __syncthreads();
    #pragma unroll
    for (int i = 0; i < 4; ++i)
        synT[(long)(n0 + ty + i*8) * N_NEURON + k0 + tx] =
            __float2bfloat16(tile[tx][ty + i*8]);
}

// -------------------------------------------------------------------------
// Kernel 2 (pep v4): ONE batch row per 512-thread block.
//  - full 32x32 grid in LDS (64 KB), periodic wrap in-block -> zero halo
//  - thread ownership chosen so phase-2 CENTERS == the thread's own staged
//    registers (sl[it]) -> no LDS round trip for c, dot done pre-barrier
//  - nontemporal stores for pep_new / firing_out / ablate copy (never
//    re-read by any kernel) -> no L2 write-allocate pollution
//  - 2 barriers total
// -------------------------------------------------------------------------
__global__ __launch_bounds__(512) void pep_fused(
    const float* __restrict__ u,
    const float* __restrict__ state,
    const float* __restrict__ noise,
    const float* __restrict__ D,
    const float* __restrict__ prod_g,
    const float* __restrict__ decay_g,
    const float* __restrict__ pact_g,
    const float* __restrict__ ndecay_g,
    const float* __restrict__ inL,
    float* __restrict__ firing_out,
    float* __restrict__ state_new,
    __hip_bfloat16* __restrict__ fbf)
{
    __shared__ floatx4 slab4[4096];      // [ (si*32+sj)*4 + pq ], 64 KB
    __shared__ float sf[N_NEURON];       // firing
    __shared__ float sn[N_NEURON];       // masked neuron
    __shared__ float sps[N_NEURON];      // peptide . pep_action

    const int b   = blockIdx.x;
    const int tid = threadIdx.x;         // 0..511
    const long bS = (long)b * S_STRIDE;
    const float u_b  = u[b];
    const float pc2  = state[bS + N_NEURON];
    const float ndecay = fabsf(ndecay_g[0]);

    const float* __restrict__ pep = state + bS + 2 * N_NEURON + N_GENES;
    float* __restrict__ pep_new = state_new + bS + 2 * N_NEURON + N_GENES;

    // per-thread p-quad constants
    const int pq = tid & 3;              // p-quad 0..3
    const int nl = tid >> 2;             // 0..127
    const int p0q = pq * 4;
    floatx4 Dq, prq, deq, paq;
    #pragma unroll
    for (int j = 0; j < 4; ++j) {
        Dq[j]  = fabsf(D[p0q + j]);
        prq[j] = fabsf(prod_g[p0q + j]);
        deq[j] = fabsf(decay_g[p0q + j]);
        paq[j] = pact_g[p0q + j];
    }

    // ---- issue all slab loads; chunk (tid + k*512) == center of iter k ----
    floatx4 sl[8];
    #pragma unroll
    for (int k = 0; k < 8; ++k)
        sl[k] = *(const floatx4u*)(pep + (tid + k * 512) * 4);

    // ---- phase-1 loads (2 neurons/thread) ----
    const int gn = tid * 2;
    floatx2 abv = *(const floatx2u*)(state + bS + gn);
    floatx2 nrv = *(const floatx2u*)(state + bS + N_NEURON + N_GENES + gn);
    floatx2 nzv = *(const floatx2*)(noise + (long)b * N_NEURON + gn);

    // ---- stage slab into LDS ----
    #pragma unroll
    for (int k = 0; k < 8; ++k)
        slab4[tid + k * 512] = sl[k];

    // ---- pact-dot from register centers (pre-barrier) ----
    #pragma unroll
    for (int k = 0; k < 8; ++k) {
        const int n = k * 128 + nl;
        float ps = sl[k][0]*paq[0] + sl[k][1]*paq[1] + sl[k][2]*paq[2] + sl[k][3]*paq[3];
        ps += __shfl_xor(ps, 1);
        ps += __shfl_xor(ps, 2);
        if (pq == 0) sps[n] = ps;
    }

    // ---- phase-1 compute ----
    {
        floatx2 fv, nmv;
        #pragma unroll
        for (int j = 0; j < 2; ++j) {
            nmv[j] = nrv[j] * abv[j];
            float fr = fmaxf(nrv[j], 0.f) * abv[j];
            fr = -(fr + 0.01f) * log1pf(-nzv[j]);
            fr = fminf(fmaxf(fr, 0.f), 10.f);
            fv[j] = fr;
        }
        __builtin_nontemporal_store(fv, (floatx2*)(firing_out + (long)b * N_NEURON + gn));
        __hip_bfloat16 h0 = __float2bfloat16(fv[0]);
        __hip_bfloat16 h1 = __float2bfloat16(fv[1]);
        unsigned int packed = (unsigned int)(*(unsigned short*)&h0) |
                              ((unsigned int)(*(unsigned short*)&h1) << 16);
        *(unsigned int*)(fbf + (long)b * N_NEURON + gn) = packed;   // re-read by gemm
        __builtin_nontemporal_store(abv, (floatx2u*)(state_new + bS + gn));
        *(floatx2*)(sf + gn) = fv;
        *(floatx2*)(sn + gn) = nmv;
    }
    if (tid == 0) state_new[bS + N_NEURON] = pc2;
    __syncthreads();

    // ---- phase 2: stencil; center from registers, neighbors from LDS ----
    #pragma unroll
    for (int it = 0; it < 8; ++it) {
        const int n  = it * 128 + nl;
        const int si = n >> 5, sj = n & 31;
        const floatx4 c  = sl[it];
        const floatx4 vu = slab4[((((si + 31) & 31) * 32) + sj) * 4 + pq];
        const floatx4 vd = slab4[((((si +  1) & 31) * 32) + sj) * 4 + pq];
        const floatx4 vl = slab4[((si * 32) + ((sj + 31) & 31)) * 4 + pq];
        const floatx4 vr = slab4[((si * 32) + ((sj +  1) & 31)) * 4 + pq];
        const float fn = sf[n];
        floatx4 lap = vu + vd + vl + vr - 4.f * c;
        floatx4 outv = c + DT_STEP * (prq * fn - deq * c + Dq * lap);
        __builtin_nontemporal_store(outv, (floatx4u*)(pep_new + (n << 4) + p0q));
    }
    __syncthreads();

    // ---- phase 3: staged c0 (2 neurons/thread; re-read by gemm -> cached) ----
    {
        floatx2 ss = *(const floatx2*)(sps + gn);
        floatx2 nm = *(const floatx2*)(sn + gn);
        floatx2 il = *(const floatx2*)(inL + gn);
        floatx2 c0;
        #pragma unroll
        for (int j = 0; j < 2; ++j)
            c0[j] = nm[j] + DT_STEP * (ss[j] * pc2 - nm[j] * ndecay + il[j] * u_b);
        *(floatx2u*)(state_new + bS + N_NEURON + N_GENES + gn) = c0;
    }
}

// -------------------------------------------------------------------------
// Kernel 3: bf16 MFMA GEMM (unchanged from last round).
// -------------------------------------------------------------------------
__device__ __forceinline__ void stage8k(const __hip_bfloat16* __restrict__ gbase,
                                        char* lhalf, int row0, int k0,
                                        int w, int lane)
{
    #pragma unroll
    for (int i = 0; i < 2; ++i) {
        const int ch  = w * 2 + i;                // 0..7, 1KB each
        const int o   = ch * 1024 + lane * 16;    // linear byte offset in half
        const int row = o >> 7;                   // 0..63
        const int c16 = (o >> 4) & 7;             // 16B chunk within row
        const int cl  = c16 ^ (row & 7);          // inverse swizzle on source
        const __hip_bfloat16* g = gbase + (long)(row0 + row) * 1024 + k0 + cl * 8;
        __builtin_amdgcn_global_load_lds(
            (const __attribute__((address_space(1))) void*)g,
            (__attribute__((address_space(3))) void*)(lhalf + ch * 1024),
            16, 0, 0);
    }
}

__device__ __forceinline__ short8 lds_frag(const char* lhalf, int row, int c16) {
    const int cl = c16 ^ (row & 7);               // swizzled read
    return *(const short8*)(lhalf + row * 128 + cl * 16);
}

__global__ __launch_bounds__(256) void gemm_epi(
    const __hip_bfloat16* __restrict__ A,   // firing bf16 [2048,1024]
    const __hip_bfloat16* __restrict__ BT,  // synT bf16 [1024,1024]
    const float* __restrict__ state,
    float* __restrict__ state_new)
{
    __shared__ __align__(16) char lds[2][16384]; // [buf][A 8KB | B 8KB]
    const int tid = threadIdx.x;
    const int w = tid >> 6, lane = tid & 63;
    const int q = lane >> 4, l16 = lane & 15;
    const int m0 = blockIdx.x * 64;
    const int n0 = blockIdx.y * 64;
    const int wm = (w & 1) * 32, wn = (w >> 1) * 32;

    // prefetch epilogue operands; latency hides under the K-loop
    float abv[2][2][4], c0v[2][2][4];
    #pragma unroll
    for (int mi = 0; mi < 2; ++mi)
    #pragma unroll
    for (int ni = 0; ni < 2; ++ni)
    #pragma unroll
    for (int r = 0; r < 4; ++r) {
        const int m = m0 + wm + mi * 16 + q * 4 + r;
        const int n = n0 + wn + ni * 16 + l16;
        const long sidx = (long)m * S_STRIDE;
        abv[mi][ni][r] = state[sidx + n];
        c0v[mi][ni][r] = state_new[sidx + N_NEURON + N_GENES + n];
    }

    floatx4 acc[2][2] = {};

    stage8k(A,  lds[0],        m0, 0, w, lane);
    stage8k(BT, lds[0] + 8192, n0, 0, w, lane);
    __syncthreads();

#define GEMM_STEP(CUR, T)                                                     \
    {                                                                         \
        if ((T) < 15) {                                                       \
            stage8k(A,  lds[(CUR) ^ 1],        m0, ((T) + 1) * 64, w, lane);  \
            stage8k(BT, lds[(CUR) ^ 1] + 8192, n0, ((T) + 1) * 64, w, lane);  \
        }                                                                     \
        const char* la = lds[(CUR)];                                          \
        const char* lb = lds[(CUR)] + 8192;                                   \
        _Pragma("unroll")                                                     \
        for (int kk = 0; kk < 2; ++kk) {                                      \
            const int c16 = kk * 4 + q;                                       \
            short8 a0 = lds_frag(la, wm + l16,      c16);                     \
            short8 a1 = lds_frag(la, wm + 16 + l16, c16);                     \
            short8 b0 = lds_frag(lb, wn + l16,      c16);                     \
            short8 b1 = lds_frag(lb, wn + 16 + l16, c16);                     \
            acc[0][0] = __builtin_amdgcn_mfma_f32_16x16x32_bf16(a0, b0, acc[0][0], 0, 0, 0); \
            acc[0][1] = __builtin_amdgcn_mfma_f32_16x16x32_bf16(a0, b1, acc[0][1], 0, 0, 0); \
            acc[1][0] = __builtin_amdgcn_mfma_f32_16x16x32_bf16(a1, b0, acc[1][0], 0, 0, 0); \
            acc[1][1] = __builtin_amdgcn_mfma_f32_16x16x32_bf16(a1, b1, acc[1][1], 0, 0, 0); \
        }                                                                     \
        if ((T) < 15) __syncthreads();                                        \
    }

    #pragma unroll
    for (int tt = 0; tt < 8; ++tt) {
        GEMM_STEP(0, tt * 2)
        GEMM_STEP(1, tt * 2 + 1)
    }
#undef GEMM_STEP

    #pragma unroll
    for (int mi = 0; mi < 2; ++mi)
    #pragma unroll
    for (int ni = 0; ni < 2; ++ni)
    #pragma unroll
    for (int r = 0; r < 4; ++r) {
        const int m = m0 + wm + mi * 16 + q * 4 + r;
        const int n = n0 + wn + ni * 16 + l16;
        const long sidx = (long)m * S_STRIDE;
        state_new[sidx + N_NEURON + N_GENES + n] =
            (c0v[mi][ni][r] + DT_STEP * acc[mi][ni][r]) * abv[mi][ni][r];
    }
}

extern "C" void kernel_launch(void* const* d_in, const int* in_sizes, int n_in,
                              void* d_out, int out_size, void* d_ws, size_t ws_size,
                              hipStream_t stream) {
    const float* u      = (const float*)d_in[0];
    const float* state  = (const float*)d_in[1];
    const float* noise  = (const float*)d_in[2];
    const float* D      = (const float*)d_in[3];
    const float* prod   = (const float*)d_in[4];
    const float* decay  = (const float*)d_in[5];
    const float* pact   = (const float*)d_in[6];
    const float* syn    = (const float*)d_in[7];
    const float* ndec   = (const float*)d_in[8];
    const float* inL    = (const float*)d_in[9];

    float* firing = (float*)d_out;                          // [B,N]
    float* state_new = firing + (long)BATCH * N_NEURON;     // [B,S]

    __hip_bfloat16* fbf  = (__hip_bfloat16*)d_ws;           // 4 MB
    __hip_bfloat16* synT = fbf + (long)BATCH * N_NEURON;    // 2 MB

    hipLaunchKernelGGL(synT_cast, dim3(32, 32), dim3(256), 0, stream, syn, synT);
    hipLaunchKernelGGL(pep_fused, dim3(BATCH), dim3(512), 0, stream,
                       u, state, noise, D, prod, decay, pact, ndec, inL,
                       firing, state_new, fbf);
    hipLaunchKernelGGL(gemm_epi, dim3(32, 16), dim3(256), 0, stream,
                       fbf, synT, state, state_new);
}